// Round 1
// baseline (2235.584 us; speedup 1.0000x reference)
//
#include <hip/hip_runtime.h>
#include <hip/hip_bf16.h>

// Problem constants
#define R_TOT   8192
#define A14     14
#define XD      3
#define N0_     256
#define NH_     8
#define A_TOT   (R_TOT * A14)     // 114688
#define QR_ELEMS (R_TOT * 256)    // 2097152

// ---------------------------------------------------------------------------
// Kernel 1: fused  z = [q, sqrt(sum_x p^2 + 1e-6)]  ->  3-layer sam MLP -> sa
// 16 atoms (rows) per block, 256 threads. Transposed LDS tiles so the inner
// GEMM loop does broadcast float4 LDS reads + coalesced float4 weight reads.
// ---------------------------------------------------------------------------
__global__ __launch_bounds__(256) void sam_kernel(
    const float* __restrict__ q, const float* __restrict__ p,
    const float* __restrict__ w1, const float* __restrict__ b1,
    const float* __restrict__ w2, const float* __restrict__ b2,
    const float* __restrict__ w3, const float* __restrict__ b3,
    float* __restrict__ sa)
{
    __shared__ float zt[512][20];    // 40 KB, z transposed: zt[k][m]
    __shared__ float h1t[256][20];   // 20 KB, h1 transposed
    // h2 transposed aliases zt rows 0..255 (zt dead after layer 1)

    const int tid = threadIdx.x;
    const int a0  = blockIdx.x * 16;

    // ---- phase 0: build z (transposed) ----
    {
        const int c = tid;  // 0..255
        #pragma unroll 4
        for (int m = 0; m < 16; ++m) {
            const size_t arow = (size_t)(a0 + m);
            zt[c][m] = q[arow * 256 + c];
            float p0 = p[arow * 768 + 0 * 256 + c];
            float p1 = p[arow * 768 + 1 * 256 + c];
            float p2 = p[arow * 768 + 2 * 256 + c];
            zt[256 + c][m] = sqrtf(p0 * p0 + p1 * p1 + p2 * p2 + 1e-6f);
        }
    }
    __syncthreads();

    const int c0 = (tid & 63) * 4;   // 4 output cols
    const int m0 = (tid >> 6) * 4;   // 4 rows (wave-uniform -> LDS broadcast)

    float acc[16];

    // ---- layer 1: 512 -> 256, leaky ----
    {
        #pragma unroll
        for (int r = 0; r < 4; ++r)
            #pragma unroll
            for (int j = 0; j < 4; ++j)
                acc[r * 4 + j] = b1[c0 + j];
        #pragma unroll 4
        for (int k = 0; k < 512; ++k) {
            const float4 zv = *(const float4*)&zt[k][m0];
            const float4 wv = *(const float4*)&w1[(size_t)k * 256 + c0];
            const float zr[4] = {zv.x, zv.y, zv.z, zv.w};
            const float wr[4] = {wv.x, wv.y, wv.z, wv.w};
            #pragma unroll
            for (int r = 0; r < 4; ++r)
                #pragma unroll
                for (int j = 0; j < 4; ++j)
                    acc[r * 4 + j] = fmaf(zr[r], wr[j], acc[r * 4 + j]);
        }
        #pragma unroll
        for (int r = 0; r < 4; ++r)
            #pragma unroll
            for (int j = 0; j < 4; ++j) {
                float v = acc[r * 4 + j];
                v = v >= 0.f ? v : 0.01f * v;
                h1t[c0 + j][m0 + r] = v;
            }
    }
    __syncthreads();

    // ---- layer 2: 256 -> 256, leaky ----
    {
        #pragma unroll
        for (int r = 0; r < 4; ++r)
            #pragma unroll
            for (int j = 0; j < 4; ++j)
                acc[r * 4 + j] = b2[c0 + j];
        #pragma unroll 4
        for (int k = 0; k < 256; ++k) {
            const float4 zv = *(const float4*)&h1t[k][m0];
            const float4 wv = *(const float4*)&w2[(size_t)k * 256 + c0];
            const float zr[4] = {zv.x, zv.y, zv.z, zv.w};
            const float wr[4] = {wv.x, wv.y, wv.z, wv.w};
            #pragma unroll
            for (int r = 0; r < 4; ++r)
                #pragma unroll
                for (int j = 0; j < 4; ++j)
                    acc[r * 4 + j] = fmaf(zr[r], wr[j], acc[r * 4 + j]);
        }
        #pragma unroll
        for (int r = 0; r < 4; ++r)
            #pragma unroll
            for (int j = 0; j < 4; ++j) {
                float v = acc[r * 4 + j];
                v = v >= 0.f ? v : 0.01f * v;
                zt[c0 + j][m0 + r] = v;   // h2t aliases zt
            }
    }
    __syncthreads();

    // ---- layer 3: 256 -> 16, no activation ----
    {
        const int m = tid >> 4;   // 0..15 row
        const int c = tid & 15;   // 0..15 col
        float a3 = b3[c];
        #pragma unroll 4
        for (int k = 0; k < 256; ++k)
            a3 = fmaf(zt[k][m], w3[(size_t)k * 16 + c], a3);
        sa[(size_t)(a0 + m) * 16 + c] = a3;
    }
}

// ---------------------------------------------------------------------------
// Kernel 2: per-residue masked softmax over 14 atoms (16 channels) + pooling
// qh[c,h] = sum_a q*aw0 ; ph[x,c,h] = sum_a p*aw1 ; stored bf16, res_mask folded.
// One block (256 threads) per residue.
// ---------------------------------------------------------------------------
__global__ __launch_bounds__(256) void pool_kernel(
    const float* __restrict__ q, const float* __restrict__ p,
    const float* __restrict__ atom_mask, const float* __restrict__ sa,
    __hip_bfloat16* __restrict__ qh, __hip_bfloat16* __restrict__ ph)
{
    __shared__ float sl[14][16];
    __shared__ float lm[14];
    __shared__ float aw0[14][8];
    __shared__ float aw1[14][8];
    __shared__ float rmask;

    const int r = blockIdx.x;
    const int tid = threadIdx.x;

    if (tid < 14) {
        float m = atom_mask[(size_t)r * 14 + tid];
        lm[tid] = (1.0f - m + 1e-6f) / (m - 1e-6f);
    }
    if (tid == 0) {
        float any = 0.f;
        #pragma unroll
        for (int a = 0; a < 14; ++a) any = fmaxf(any, atom_mask[(size_t)r * 14 + a]);
        rmask = (any != 0.f) ? 1.f : 0.f;
    }
    __syncthreads();

    if (tid < 224) {
        int a = tid >> 4, ch = tid & 15;
        sl[a][ch] = sa[((size_t)r * 14 + a) * 16 + ch] + lm[a];
    }
    __syncthreads();

    if (tid < 16) {
        const int ch = tid;
        float mx = -3.0e38f;
        #pragma unroll
        for (int a = 0; a < 14; ++a) mx = fmaxf(mx, sl[a][ch]);
        float e[14];
        float s = 0.f;
        #pragma unroll
        for (int a = 0; a < 14; ++a) { e[a] = expf(sl[a][ch] - mx); s += e[a]; }
        const float inv = rmask / s;   // fold residue mask into weights
        #pragma unroll
        for (int a = 0; a < 14; ++a) {
            float v = e[a] * inv;
            if (ch & 1) aw1[a][ch >> 1] = v;
            else        aw0[a][ch >> 1] = v;
        }
    }
    __syncthreads();

    const int c = tid;  // 0..255

    // qh pooling
    {
        float acc[8] = {0, 0, 0, 0, 0, 0, 0, 0};
        #pragma unroll
        for (int a = 0; a < 14; ++a) {
            const float qv = q[((size_t)r * 14 + a) * 256 + c];
            #pragma unroll
            for (int h = 0; h < 8; ++h) acc[h] = fmaf(qv, aw0[a][h], acc[h]);
        }
        alignas(16) __hip_bfloat16 tmp[8];
        #pragma unroll
        for (int h = 0; h < 8; ++h) tmp[h] = __float2bfloat16(acc[h]);
        *reinterpret_cast<int4*>(&qh[(size_t)r * 2048 + (size_t)c * 8]) =
            *reinterpret_cast<const int4*>(tmp);
    }
    // ph pooling
    for (int x = 0; x < 3; ++x) {
        float acc[8] = {0, 0, 0, 0, 0, 0, 0, 0};
        #pragma unroll
        for (int a = 0; a < 14; ++a) {
            const float pv = p[((size_t)r * 14 + a) * 768 + (size_t)x * 256 + c];
            #pragma unroll
            for (int h = 0; h < 8; ++h) acc[h] = fmaf(pv, aw1[a][h], acc[h]);
        }
        alignas(16) __hip_bfloat16 tmp[8];
        #pragma unroll
        for (int h = 0; h < 8; ++h) tmp[h] = __float2bfloat16(acc[h]);
        *reinterpret_cast<int4*>(&ph[((size_t)r * 3 + x) * 2048 + (size_t)c * 8]) =
            *reinterpret_cast<const int4*>(tmp);
    }
}

// ---------------------------------------------------------------------------
// Kernels 3-6: generic  out[M,256] = act(x[M,K] @ w[K,256] (+ bias))
// 16 rows per block, 256 threads, K staged in transposed LDS chunks.
// ---------------------------------------------------------------------------
template <int K, bool BF16IN, bool BIAS, bool LEAKY>
__global__ __launch_bounds__(256) void mlp_kernel(
    const void* __restrict__ xin, const float* __restrict__ w,
    const float* __restrict__ bias, float* __restrict__ out)
{
    constexpr int KC = (K > 512) ? 512 : K;
    __shared__ float xt[KC][20];   // transposed x chunk: xt[k][m]  (<=40KB)

    const int tid = threadIdx.x;
    const int a0  = blockIdx.x * 16;
    const int c0  = (tid & 63) * 4;
    const int m0  = (tid >> 6) * 4;

    float acc[16];
    #pragma unroll
    for (int r = 0; r < 4; ++r)
        #pragma unroll
        for (int j = 0; j < 4; ++j)
            acc[r * 4 + j] = BIAS ? bias[c0 + j] : 0.0f;

    for (int chunk = 0; chunk < K; chunk += KC) {
        __syncthreads();
        // stage chunk, transposed
        for (int m = 0; m < 16; ++m) {
            const size_t base = (size_t)(a0 + m) * K + chunk;
            #pragma unroll
            for (int k = tid; k < KC; k += 256) {
                float v;
                if (BF16IN)
                    v = __bfloat162float(((const __hip_bfloat16*)xin)[base + k]);
                else
                    v = ((const float*)xin)[base + k];
                xt[k][m] = v;
            }
        }
        __syncthreads();

        #pragma unroll 4
        for (int k = 0; k < KC; ++k) {
            const float4 zv = *(const float4*)&xt[k][m0];
            const float4 wv = *(const float4*)&w[(size_t)(chunk + k) * 256 + c0];
            const float zr[4] = {zv.x, zv.y, zv.z, zv.w};
            const float wr[4] = {wv.x, wv.y, wv.z, wv.w};
            #pragma unroll
            for (int r = 0; r < 4; ++r)
                #pragma unroll
                for (int j = 0; j < 4; ++j)
                    acc[r * 4 + j] = fmaf(zr[r], wr[j], acc[r * 4 + j]);
        }
    }

    #pragma unroll
    for (int r = 0; r < 4; ++r) {
        float4 o;
        float v0 = acc[r * 4 + 0], v1 = acc[r * 4 + 1];
        float v2 = acc[r * 4 + 2], v3 = acc[r * 4 + 3];
        if (LEAKY) {
            v0 = v0 >= 0.f ? v0 : 0.01f * v0;
            v1 = v1 >= 0.f ? v1 : 0.01f * v1;
            v2 = v2 >= 0.f ? v2 : 0.01f * v2;
            v3 = v3 >= 0.f ? v3 : 0.01f * v3;
        }
        o.x = v0; o.y = v1; o.z = v2; o.w = v3;
        *(float4*)&out[(size_t)(a0 + m0 + r) * 256 + c0] = o;
    }
}

// ---------------------------------------------------------------------------
extern "C" void kernel_launch(void* const* d_in, const int* in_sizes, int n_in,
                              void* d_out, int out_size, void* d_ws, size_t ws_size,
                              hipStream_t stream)
{
    const float* q    = (const float*)d_in[0];
    const float* p    = (const float*)d_in[1];
    const float* amsk = (const float*)d_in[2];
    const float* sw1  = (const float*)d_in[3];
    const float* sb1  = (const float*)d_in[4];
    const float* sw2  = (const float*)d_in[5];
    const float* sb2  = (const float*)d_in[6];
    const float* sw3  = (const float*)d_in[7];
    const float* sb3  = (const float*)d_in[8];
    const float* zw1  = (const float*)d_in[9];
    const float* zb1  = (const float*)d_in[10];
    const float* zw2  = (const float*)d_in[11];
    const float* zb2  = (const float*)d_in[12];
    const float* zw3  = (const float*)d_in[13];
    const float* zb3  = (const float*)d_in[14];
    const float* zvw  = (const float*)d_in[15];

    // workspace carve-up (151 MB total)
    char* ws = (char*)d_ws;
    float* sa            = (float*)ws;                               // 7,340,032 B
    __hip_bfloat16* qh   = (__hip_bfloat16*)(ws + 7340032);          // 33,554,432 B
    __hip_bfloat16* ph   = (__hip_bfloat16*)(ws + 7340032 + 33554432);  // 100,663,296 B
    float* h1            = (float*)(ws + 141557760);                 // 8,388,608 B
    float* h2            = (float*)(ws + 141557760 + 8388608);       // 8,388,608 B

    float* qr = (float*)d_out;
    float* pr = (float*)d_out + QR_ELEMS;

    // 1) sam MLP over all atoms
    sam_kernel<<<A_TOT / 16, 256, 0, stream>>>(q, p, sw1, sb1, sw2, sb2, sw3, sb3, sa);
    // 2) softmax + pooling per residue
    pool_kernel<<<R_TOT, 256, 0, stream>>>(q, p, amsk, sa, qh, ph);
    // 3-5) zdm MLP
    mlp_kernel<2048, true,  true,  true ><<<R_TOT / 16, 256, 0, stream>>>(qh, zw1, zb1, h1);
    mlp_kernel<256,  false, true,  true ><<<R_TOT / 16, 256, 0, stream>>>(h1, zw2, zb2, h2);
    mlp_kernel<256,  false, true,  false><<<R_TOT / 16, 256, 0, stream>>>(h2, zw3, zb3, qr);
    // 6) pr = ph_flat @ zdm_vec_w
    mlp_kernel<2048, true,  false, false><<<(R_TOT * 3) / 16, 256, 0, stream>>>(ph, zvw, nullptr, pr);

    (void)in_sizes; (void)n_in; (void)out_size; (void)ws_size;
}

// Round 2
// 597.134 us; speedup vs baseline: 3.7439x; 3.7439x over previous
//
#include <hip/hip_runtime.h>
#include <hip/hip_bf16.h>

// Problem constants
#define R_TOT   8192
#define A14     14
#define A_TOT   (R_TOT * A14)     // 114688
#define QR_ELEMS (R_TOT * 256)    // 2097152

typedef __attribute__((ext_vector_type(8))) short bf16x8;
typedef __attribute__((ext_vector_type(4))) float f32x4;
typedef __attribute__((ext_vector_type(4))) short short4v;

#define MFMA16(a, b, c) __builtin_amdgcn_mfma_f32_16x16x32_bf16((a), (b), (c), 0, 0, 0)

static __device__ __forceinline__ float bf2f(__hip_bfloat16 v) { return __bfloat162float(v); }

// ---------------------------------------------------------------------------
// Weight transpose + bf16 cast:  w[K][N] fp32  ->  wT[N][K] bf16
// ---------------------------------------------------------------------------
__global__ __launch_bounds__(256) void wtrans_kernel(
    const float* __restrict__ w, __hip_bfloat16* __restrict__ wT, int K, int N)
{
    __shared__ float tile[32][33];
    const int kb = blockIdx.x * 32, nb = blockIdx.y * 32;
    const int tx = threadIdx.x & 31, ty = threadIdx.x >> 5;   // 32 x 8
    #pragma unroll
    for (int i = 0; i < 32; i += 8) {
        int k = kb + ty + i, n = nb + tx;
        tile[ty + i][tx] = (k < K && n < N) ? w[(size_t)k * N + n] : 0.f;
    }
    __syncthreads();
    #pragma unroll
    for (int i = 0; i < 32; i += 8) {
        int n = nb + ty + i, k = kb + tx;
        if (n < N && k < K) wT[(size_t)n * K + k] = __float2bfloat16(tile[tx][ty + i]);
    }
}

// ---------------------------------------------------------------------------
// Fused sam MLP (bf16 MFMA): z=[q, ||p||] -> 512->256->256->16
// 32 atoms per block, 256 threads = 4 waves; waves split N (64 cols each).
// ---------------------------------------------------------------------------
__global__ __launch_bounds__(256) void sam_mfma_kernel(
    const float* __restrict__ q, const float* __restrict__ p,
    const __hip_bfloat16* __restrict__ wT1, const float* __restrict__ b1,
    const __hip_bfloat16* __restrict__ wT2, const float* __restrict__ b2,
    const __hip_bfloat16* __restrict__ wT3, const float* __restrict__ b3,
    float* __restrict__ sa)
{
    __shared__ __hip_bfloat16 zlds[32][520];    // 33,280 B ; row stride 1040B = 4 banks mod 32
    __shared__ __hip_bfloat16 h1lds[32][264];   // 16,896 B ; row stride 528B
    __hip_bfloat16 (* const h2lds)[264] = (__hip_bfloat16(*)[264])&zlds[0][0];  // alias (z dead after L1)

    const int tid = threadIdx.x;
    const int a0  = blockIdx.x * 32;
    const int wv  = tid >> 6;
    const int l   = tid & 63;
    const int lr  = l & 15;         // row (A) / col (B,D)
    const int lh  = l >> 4;         // k-group / D row-group
    const int nbase = wv * 64;

    // ---- stage z as bf16 ----
    for (int idx = tid; idx < 32 * 128; idx += 256) {
        const int m  = idx >> 7;
        const int c4 = (idx & 127) * 4;
        const size_t arow = (size_t)(a0 + m);
        __hip_bfloat16 t[4];
        if (c4 < 256) {
            const float4 qv = *(const float4*)&q[arow * 256 + c4];
            t[0] = __float2bfloat16(qv.x); t[1] = __float2bfloat16(qv.y);
            t[2] = __float2bfloat16(qv.z); t[3] = __float2bfloat16(qv.w);
        } else {
            const int cc = c4 - 256;
            const float4 pa = *(const float4*)&p[arow * 768 + 0 * 256 + cc];
            const float4 pb = *(const float4*)&p[arow * 768 + 1 * 256 + cc];
            const float4 pc = *(const float4*)&p[arow * 768 + 2 * 256 + cc];
            t[0] = __float2bfloat16(sqrtf(pa.x*pa.x + pb.x*pb.x + pc.x*pc.x + 1e-6f));
            t[1] = __float2bfloat16(sqrtf(pa.y*pa.y + pb.y*pb.y + pc.y*pc.y + 1e-6f));
            t[2] = __float2bfloat16(sqrtf(pa.z*pa.z + pb.z*pb.z + pc.z*pc.z + 1e-6f));
            t[3] = __float2bfloat16(sqrtf(pa.w*pa.w + pb.w*pb.w + pc.w*pc.w + 1e-6f));
        }
        *(short4v*)&zlds[m][c4] = *(const short4v*)t;
    }
    __syncthreads();

    // ---- layer 1: K=512 -> N=256, leaky ----
    {
        f32x4 acc[2][4] = {};
        for (int k0 = 0; k0 < 512; k0 += 32) {
            const int kc = k0 + lh * 8;
            bf16x8 af0 = *(const bf16x8*)&zlds[lr][kc];
            bf16x8 af1 = *(const bf16x8*)&zlds[16 + lr][kc];
            bf16x8 bf[4];
            #pragma unroll
            for (int nt = 0; nt < 4; ++nt)
                bf[nt] = *(const bf16x8*)&wT1[(size_t)(nbase + nt * 16 + lr) * 512 + kc];
            #pragma unroll
            for (int nt = 0; nt < 4; ++nt) {
                acc[0][nt] = MFMA16(af0, bf[nt], acc[0][nt]);
                acc[1][nt] = MFMA16(af1, bf[nt], acc[1][nt]);
            }
        }
        #pragma unroll
        for (int nt = 0; nt < 4; ++nt) {
            const int n = nbase + nt * 16 + lr;
            const float bv = b1[n];
            #pragma unroll
            for (int mt = 0; mt < 2; ++mt)
                #pragma unroll
                for (int v = 0; v < 4; ++v) {
                    float x = acc[mt][nt][v] + bv;
                    x = x >= 0.f ? x : 0.01f * x;
                    h1lds[mt * 16 + lh * 4 + v][n] = __float2bfloat16(x);
                }
        }
    }
    __syncthreads();

    // ---- layer 2: K=256 -> N=256, leaky (out into zlds alias) ----
    {
        f32x4 acc[2][4] = {};
        for (int k0 = 0; k0 < 256; k0 += 32) {
            const int kc = k0 + lh * 8;
            bf16x8 af0 = *(const bf16x8*)&h1lds[lr][kc];
            bf16x8 af1 = *(const bf16x8*)&h1lds[16 + lr][kc];
            bf16x8 bf[4];
            #pragma unroll
            for (int nt = 0; nt < 4; ++nt)
                bf[nt] = *(const bf16x8*)&wT2[(size_t)(nbase + nt * 16 + lr) * 256 + kc];
            #pragma unroll
            for (int nt = 0; nt < 4; ++nt) {
                acc[0][nt] = MFMA16(af0, bf[nt], acc[0][nt]);
                acc[1][nt] = MFMA16(af1, bf[nt], acc[1][nt]);
            }
        }
        __syncthreads();   // all waves done reading zlds (L1 A-frags long done) before h2 overwrite
        #pragma unroll
        for (int nt = 0; nt < 4; ++nt) {
            const int n = nbase + nt * 16 + lr;
            const float bv = b2[n];
            #pragma unroll
            for (int mt = 0; mt < 2; ++mt)
                #pragma unroll
                for (int v = 0; v < 4; ++v) {
                    float x = acc[mt][nt][v] + bv;
                    x = x >= 0.f ? x : 0.01f * x;
                    h2lds[mt * 16 + lh * 4 + v][n] = __float2bfloat16(x);
                }
        }
    }
    __syncthreads();

    // ---- layer 3: K=256 -> N=16 (waves 0,1 only; no activation) ----
    if (wv < 2) {
        f32x4 acc = {};
        for (int k0 = 0; k0 < 256; k0 += 32) {
            const int kc = k0 + lh * 8;
            bf16x8 af = *(const bf16x8*)&h2lds[wv * 16 + lr][kc];
            bf16x8 bf = *(const bf16x8*)&wT3[(size_t)lr * 256 + kc];
            acc = MFMA16(af, bf, acc);
        }
        const float bv = b3[lr];
        #pragma unroll
        for (int v = 0; v < 4; ++v) {
            const int m = wv * 16 + lh * 4 + v;
            sa[(size_t)(a0 + m) * 16 + lr] = acc[v] + bv;
        }
    }
}

// ---------------------------------------------------------------------------
// Kernel 2: per-residue masked softmax over 14 atoms + pooling (unchanged)
// ---------------------------------------------------------------------------
__global__ __launch_bounds__(256) void pool_kernel(
    const float* __restrict__ q, const float* __restrict__ p,
    const float* __restrict__ atom_mask, const float* __restrict__ sa,
    __hip_bfloat16* __restrict__ qh, __hip_bfloat16* __restrict__ ph)
{
    __shared__ float sl[14][16];
    __shared__ float lm[14];
    __shared__ float aw0[14][8];
    __shared__ float aw1[14][8];
    __shared__ float rmask;

    const int r = blockIdx.x;
    const int tid = threadIdx.x;

    if (tid < 14) {
        float m = atom_mask[(size_t)r * 14 + tid];
        lm[tid] = (1.0f - m + 1e-6f) / (m - 1e-6f);
    }
    if (tid == 0) {
        float any = 0.f;
        #pragma unroll
        for (int a = 0; a < 14; ++a) any = fmaxf(any, atom_mask[(size_t)r * 14 + a]);
        rmask = (any != 0.f) ? 1.f : 0.f;
    }
    __syncthreads();

    if (tid < 224) {
        int a = tid >> 4, ch = tid & 15;
        sl[a][ch] = sa[((size_t)r * 14 + a) * 16 + ch] + lm[a];
    }
    __syncthreads();

    if (tid < 16) {
        const int ch = tid;
        float mx = -3.0e38f;
        #pragma unroll
        for (int a = 0; a < 14; ++a) mx = fmaxf(mx, sl[a][ch]);
        float e[14];
        float s = 0.f;
        #pragma unroll
        for (int a = 0; a < 14; ++a) { e[a] = expf(sl[a][ch] - mx); s += e[a]; }
        const float inv = rmask / s;
        #pragma unroll
        for (int a = 0; a < 14; ++a) {
            float v = e[a] * inv;
            if (ch & 1) aw1[a][ch >> 1] = v;
            else        aw0[a][ch >> 1] = v;
        }
    }
    __syncthreads();

    const int c = tid;

    {
        float acc[8] = {0, 0, 0, 0, 0, 0, 0, 0};
        #pragma unroll
        for (int a = 0; a < 14; ++a) {
            const float qv = q[((size_t)r * 14 + a) * 256 + c];
            #pragma unroll
            for (int h = 0; h < 8; ++h) acc[h] = fmaf(qv, aw0[a][h], acc[h]);
        }
        alignas(16) __hip_bfloat16 tmp[8];
        #pragma unroll
        for (int h = 0; h < 8; ++h) tmp[h] = __float2bfloat16(acc[h]);
        *reinterpret_cast<int4*>(&qh[(size_t)r * 2048 + (size_t)c * 8]) =
            *reinterpret_cast<const int4*>(tmp);
    }
    for (int x = 0; x < 3; ++x) {
        float acc[8] = {0, 0, 0, 0, 0, 0, 0, 0};
        #pragma unroll
        for (int a = 0; a < 14; ++a) {
            const float pv = p[((size_t)r * 14 + a) * 768 + (size_t)x * 256 + c];
            #pragma unroll
            for (int h = 0; h < 8; ++h) acc[h] = fmaf(pv, aw1[a][h], acc[h]);
        }
        alignas(16) __hip_bfloat16 tmp[8];
        #pragma unroll
        for (int h = 0; h < 8; ++h) tmp[h] = __float2bfloat16(acc[h]);
        *reinterpret_cast<int4*>(&ph[((size_t)r * 3 + x) * 2048 + (size_t)c * 8]) =
            *reinterpret_cast<const int4*>(tmp);
    }
}

// ---------------------------------------------------------------------------
// Generic bf16-MFMA MLP layer: out[M,256] = act(x[M,K] @ w[K,256] (+bias))
// x bf16, wT bf16 [256][K]. 32 rows/block, 4 waves (64 cols each).
// ---------------------------------------------------------------------------
template <int K, bool BIAS, bool LEAKY, bool OUT_BF16>
__global__ __launch_bounds__(256) void mlp_mfma_kernel(
    const __hip_bfloat16* __restrict__ x, const __hip_bfloat16* __restrict__ wT,
    const float* __restrict__ bias, void* __restrict__ out)
{
    constexpr int KC = (K < 256) ? K : 256;
    __shared__ __hip_bfloat16 xlds[32][KC + 8];

    const int tid = threadIdx.x;
    const int a0  = blockIdx.x * 32;
    const int wv  = tid >> 6;
    const int l   = tid & 63;
    const int lr  = l & 15;
    const int lh  = l >> 4;
    const int nbase = wv * 64;

    f32x4 acc[2][4] = {};

    for (int chunk = 0; chunk < K; chunk += KC) {
        __syncthreads();
        for (int u = tid; u < 32 * (KC / 8); u += 256) {
            const int m  = u / (KC / 8);
            const int c8 = (u % (KC / 8)) * 8;
            const int4 v = *(const int4*)&x[(size_t)(a0 + m) * K + chunk + c8];
            *(int4*)&xlds[m][c8] = v;
        }
        __syncthreads();

        #pragma unroll 2
        for (int k0 = 0; k0 < KC; k0 += 32) {
            const int kc = k0 + lh * 8;
            bf16x8 af0 = *(const bf16x8*)&xlds[lr][kc];
            bf16x8 af1 = *(const bf16x8*)&xlds[16 + lr][kc];
            bf16x8 bf[4];
            #pragma unroll
            for (int nt = 0; nt < 4; ++nt)
                bf[nt] = *(const bf16x8*)&wT[(size_t)(nbase + nt * 16 + lr) * K + chunk + kc];
            #pragma unroll
            for (int nt = 0; nt < 4; ++nt) {
                acc[0][nt] = MFMA16(af0, bf[nt], acc[0][nt]);
                acc[1][nt] = MFMA16(af1, bf[nt], acc[1][nt]);
            }
        }
    }

    #pragma unroll
    for (int nt = 0; nt < 4; ++nt) {
        const int n = nbase + nt * 16 + lr;
        const float bv = BIAS ? bias[n] : 0.0f;
        #pragma unroll
        for (int mt = 0; mt < 2; ++mt)
            #pragma unroll
            for (int v = 0; v < 4; ++v) {
                float xv = acc[mt][nt][v] + bv;
                if (LEAKY) xv = xv >= 0.f ? xv : 0.01f * xv;
                const size_t oidx = (size_t)(a0 + mt * 16 + lh * 4 + v) * 256 + n;
                if (OUT_BF16) ((__hip_bfloat16*)out)[oidx] = __float2bfloat16(xv);
                else          ((float*)out)[oidx] = xv;
            }
    }
}

// ---------------------------------------------------------------------------
extern "C" void kernel_launch(void* const* d_in, const int* in_sizes, int n_in,
                              void* d_out, int out_size, void* d_ws, size_t ws_size,
                              hipStream_t stream)
{
    const float* q    = (const float*)d_in[0];
    const float* p    = (const float*)d_in[1];
    const float* amsk = (const float*)d_in[2];
    const float* sw1  = (const float*)d_in[3];
    const float* sb1  = (const float*)d_in[4];
    const float* sw2  = (const float*)d_in[5];
    const float* sb2  = (const float*)d_in[6];
    const float* sw3  = (const float*)d_in[7];
    const float* sb3  = (const float*)d_in[8];
    const float* zw1  = (const float*)d_in[9];
    const float* zb1  = (const float*)d_in[10];
    const float* zw2  = (const float*)d_in[11];
    const float* zb2  = (const float*)d_in[12];
    const float* zw3  = (const float*)d_in[13];
    const float* zb3  = (const float*)d_in[14];
    const float* zvw  = (const float*)d_in[15];

    // workspace carve-up
    char* ws = (char*)d_ws;
    size_t off = 0;
    float* sa            = (float*)(ws + off);           off += (size_t)A_TOT * 16 * 4;        // 7,340,032
    __hip_bfloat16* qh   = (__hip_bfloat16*)(ws + off);  off += (size_t)R_TOT * 2048 * 2;      // 33,554,432
    __hip_bfloat16* ph   = (__hip_bfloat16*)(ws + off);  off += (size_t)R_TOT * 3 * 2048 * 2;  // 100,663,296
    __hip_bfloat16* h1   = (__hip_bfloat16*)(ws + off);  off += (size_t)R_TOT * 256 * 2;       // 4,194,304
    __hip_bfloat16* h2   = (__hip_bfloat16*)(ws + off);  off += (size_t)R_TOT * 256 * 2;       // 4,194,304
    __hip_bfloat16* wT1  = (__hip_bfloat16*)(ws + off);  off += 256 * 512 * 2;
    __hip_bfloat16* wT2  = (__hip_bfloat16*)(ws + off);  off += 256 * 256 * 2;
    __hip_bfloat16* wT3  = (__hip_bfloat16*)(ws + off);  off += 16 * 256 * 2;
    __hip_bfloat16* zT1  = (__hip_bfloat16*)(ws + off);  off += 256 * 2048 * 2;
    __hip_bfloat16* zT2  = (__hip_bfloat16*)(ws + off);  off += 256 * 256 * 2;
    __hip_bfloat16* zT3  = (__hip_bfloat16*)(ws + off);  off += 256 * 256 * 2;
    __hip_bfloat16* vT   = (__hip_bfloat16*)(ws + off);  off += 256 * 2048 * 2;

    float* qr = (float*)d_out;
    float* pr = (float*)d_out + QR_ELEMS;

    // 0) weight transpose + bf16 cast
    wtrans_kernel<<<dim3(16, 8), 256, 0, stream>>>(sw1, wT1, 512, 256);
    wtrans_kernel<<<dim3(8, 8),  256, 0, stream>>>(sw2, wT2, 256, 256);
    wtrans_kernel<<<dim3(8, 1),  256, 0, stream>>>(sw3, wT3, 256, 16);
    wtrans_kernel<<<dim3(64, 8), 256, 0, stream>>>(zw1, zT1, 2048, 256);
    wtrans_kernel<<<dim3(8, 8),  256, 0, stream>>>(zw2, zT2, 256, 256);
    wtrans_kernel<<<dim3(8, 8),  256, 0, stream>>>(zw3, zT3, 256, 256);
    wtrans_kernel<<<dim3(64, 8), 256, 0, stream>>>(zvw, vT, 2048, 256);

    // 1) fused sam MLP (bf16 MFMA)
    sam_mfma_kernel<<<A_TOT / 32, 256, 0, stream>>>(q, p, wT1, sb1, wT2, sb2, wT3, sb3, sa);
    // 2) softmax + pooling per residue
    pool_kernel<<<R_TOT, 256, 0, stream>>>(q, p, amsk, sa, qh, ph);
    // 3-5) zdm MLP (bf16 MFMA)
    mlp_mfma_kernel<2048, true,  true,  true ><<<R_TOT / 32, 256, 0, stream>>>(qh, zT1, zb1, h1);
    mlp_mfma_kernel<256,  true,  true,  true ><<<R_TOT / 32, 256, 0, stream>>>(h1, zT2, zb2, h2);
    mlp_mfma_kernel<256,  true,  false, false><<<R_TOT / 32, 256, 0, stream>>>(h2, zT3, zb3, qr);
    // 6) pr = ph @ zdm_vec_w (bf16 MFMA)
    mlp_mfma_kernel<2048, false, false, false><<<(R_TOT * 3) / 32, 256, 0, stream>>>(ph, vT, nullptr, pr);

    (void)in_sizes; (void)n_in; (void)out_size; (void)ws_size;
}